// Round 6
// baseline (166.309 us; speedup 1.0000x reference)
//
#include <hip/hip_runtime.h>

#define SEQ 4096
#define EMB 768
#define NH 12
#define HD 64
#define KDIM 768
#define LNEG -100000000.0f
#define LOG2E 1.44269504f
#define PSTR2 580   // Pb row stride (shorts): 290 words == 2 mod 32 -> uniform banks

typedef __attribute__((ext_vector_type(8))) short short8;
typedef __attribute__((ext_vector_type(4))) short short4v;
typedef __attribute__((ext_vector_type(4))) float f32x4;

__device__ inline unsigned short f2bf(float f) {
    unsigned int u = __float_as_uint(f);
    u += 0x7fffu + ((u >> 16) & 1u);
    return (unsigned short)(u >> 16);
}
__device__ inline float bf2f(unsigned short s) {
    unsigned int u = ((unsigned int)s) << 16;
    return __uint_as_float(u);
}

__device__ inline void gload_lds16(const unsigned short* g, unsigned short* l) {
    __builtin_amdgcn_global_load_lds(
        (const __attribute__((address_space(1))) void*)g,
        (__attribute__((address_space(3))) void*)l, 16, 0, 0);
}

// ---------------- Prep: hid -> bf16, W -> W^T bf16 (q-scale*log2e folded into Wq) ----------------
// grid 1008 linear: WGs 0..431 = W transpose tiles (3 mats x 144), 432..1007 = hid convert.
__global__ __launch_bounds__(256) void prep_kernel(
    const float* __restrict__ hid,
    const float* __restrict__ Wq, const float* __restrict__ Wk, const float* __restrict__ Wv,
    unsigned short* __restrict__ hidb,   // [4096][768] bf16
    unsigned short* __restrict__ Wt)     // [2304][768] bf16, [n][k]
{
    const int bid = blockIdx.x;
    const int t = threadIdx.x;
    if (bid >= 432) {
        int vid = (bid - 432) * 256 + t;
        const int nch = SEQ * EMB / 4;
        const int stride = 576 * 256;
        for (int c = vid; c < nch; c += stride) {
            f32x4 v = ((const f32x4*)hid)[c];
            short4v o;
            #pragma unroll
            for (int x = 0; x < 4; x++) o[x] = (short)f2bf(v[x]);
            ((short4v*)hidb)[c] = o;
        }
        return;
    }
    const int mat = bid / 144;
    const int r2 = bid % 144;
    const int k0 = (r2 % 12) * 64;
    const int n0 = (r2 / 12) * 64;
    const float* Wm = (mat == 0) ? Wq : (mat == 1 ? Wk : Wv);
    const float scale = (mat == 0) ? 0.125f * LOG2E : 1.0f;
    __shared__ unsigned short Lt[64 * 82];
    #pragma unroll
    for (int i = 0; i < 4; i++) {
        int row = i * 16 + (t >> 4);
        int col = (t & 15) * 4;
        f32x4 v = *(const f32x4*)(Wm + (size_t)(k0 + row) * EMB + n0 + col);
        #pragma unroll
        for (int x = 0; x < 4; x++)
            Lt[(col + x) * 82 + row] = f2bf(v[x] * scale);
    }
    __syncthreads();
    #pragma unroll
    for (int j = 0; j < 2; j++) {
        int idx = j * 256 + t;
        int nr = idx >> 3;
        int kc = (idx & 7) * 8;
        short8 o = *(const short8*)(Lt + nr * 82 + kc);
        *(short8*)(Wt + (size_t)(mat * 768 + n0 + nr) * KDIM + k0 + kc) = o;
    }
}

// ---------------- GEMM: 128x96 tiles, grid (32,24)=768 WGs (3.0/CU); LDS-bounce epilogue ----------------
__global__ __launch_bounds__(256) void gemm_kernel(
    const unsigned short* __restrict__ hidb,
    const unsigned short* __restrict__ Wt,
    const float* __restrict__ bq, const float* __restrict__ bk, const float* __restrict__ bv,
    unsigned short* __restrict__ q_ws,   // [H][S][D] bf16
    unsigned short* __restrict__ k_ws,   // [H][S][D] bf16
    unsigned short* __restrict__ v_ws)   // [H][D][S] bf16
{
    const int m0 = blockIdx.x * 128;
    const int n0 = blockIdx.y * 96;
    __shared__ union {
        struct { unsigned short Al[128 * 64]; unsigned short Bl[96 * 64]; } s;  // 28 KB
        unsigned short Cqk[128 * 104];  // 26 KB, stride 104 (208B, 16B-aligned rows)
        unsigned short Cv[96 * 136];    // 25.5 KB, stride 136 (272B, 16B-aligned rows)
    } sm;
    const int t = threadIdx.x;
    const int wave = t >> 6, lane = t & 63;
    const int quad = lane >> 4, l16 = lane & 15;
    const int wr = wave >> 1, wc = wave & 1;   // 2x2 waves: 64m x 48n each

    const f32x4 zero = {0.f, 0.f, 0.f, 0.f};
    f32x4 acc[4][3];
    #pragma unroll
    for (int i = 0; i < 4; i++)
        #pragma unroll
        for (int j = 0; j < 3; j++) acc[i][j] = zero;

    for (int k0 = 0; k0 < KDIM; k0 += 64) {
        #pragma unroll
        for (int i = 0; i < 4; i++) {           // A: 16 instrs, 4/wave
            int c = (wave * 4 + i) * 64 + lane;
            int row = c >> 3;
            int kc = ((c & 7) ^ (row & 7)) * 8;
            gload_lds16(hidb + (size_t)(m0 + row) * KDIM + k0 + kc, sm.s.Al + (wave * 4 + i) * 512);
        }
        #pragma unroll
        for (int i = 0; i < 3; i++) {           // B: 12 instrs, 3/wave
            int c = (wave * 3 + i) * 64 + lane;
            int row = c >> 3;
            int kc = ((c & 7) ^ (row & 7)) * 8;
            gload_lds16(Wt + (size_t)(n0 + row) * KDIM + k0 + kc, sm.s.Bl + (wave * 3 + i) * 512);
        }
        __syncthreads();

        short8 af[2][4], bfr[2][3];
        #pragma unroll
        for (int rt = 0; rt < 4; rt++) {
            int rowA = wr * 64 + rt * 16 + l16;
            #pragma unroll
            for (int s = 0; s < 2; s++)
                af[s][rt] = *(const short8*)(sm.s.Al + rowA * 64 + (((s << 2) | quad) ^ (rowA & 7)) * 8);
        }
        #pragma unroll
        for (int ct = 0; ct < 3; ct++) {
            int rowB = wc * 48 + ct * 16 + l16;
            #pragma unroll
            for (int s = 0; s < 2; s++)
                bfr[s][ct] = *(const short8*)(sm.s.Bl + rowB * 64 + (((s << 2) | quad) ^ (rowB & 7)) * 8);
        }
        #pragma unroll
        for (int s = 0; s < 2; s++)
            #pragma unroll
            for (int rt = 0; rt < 4; rt++)
                #pragma unroll
                for (int ct = 0; ct < 3; ct++)
                    acc[rt][ct] = __builtin_amdgcn_mfma_f32_16x16x32_bf16(af[s][rt], bfr[s][ct], acc[rt][ct], 0, 0, 0);
        __syncthreads();
    }

    const int mat = blockIdx.y >> 3;            // 8 n-blocks of 96 per matrix
    const float* bm = (mat == 0) ? bq : (mat == 1 ? bk : bv);
    const float bscale = (mat == 0) ? 0.125f * LOG2E : 1.0f;

    if (mat != 2) {
        #pragma unroll
        for (int ct = 0; ct < 3; ct++) {
            int nloc = wc * 48 + ct * 16 + l16;
            float bias = bm[(n0 + nloc) - mat * 768] * bscale;
            #pragma unroll
            for (int rt = 0; rt < 4; rt++)
                #pragma unroll
                for (int r = 0; r < 4; r++)
                    sm.Cqk[(wr * 64 + rt * 16 + quad * 4 + r) * 104 + nloc] = f2bf(acc[rt][ct][r] + bias);
        }
        __syncthreads();
        unsigned short* dst_ws = (mat == 0) ? q_ws : k_ws;
        #pragma unroll
        for (int p = 0; p < 6; p++) {
            int id = p * 256 + t;            // 1536 = 128 rows x 12 chunks
            int row = id / 12, nc = id - row * 12;
            short8 val = *(const short8*)(sm.Cqk + row * 104 + nc * 8);
            int within = (n0 + nc * 8) - mat * 768;
            int head = within >> 6, dd = within & 63;
            *(short8*)(dst_ws + (size_t)head * (SEQ * HD) + (size_t)(m0 + row) * HD + dd) = val;
        }
    } else {
        #pragma unroll
        for (int ct = 0; ct < 3; ct++) {
            int nloc = wc * 48 + ct * 16 + l16;
            float bias = bm[(n0 + nloc) - 1536];
            #pragma unroll
            for (int rt = 0; rt < 4; rt++)
                #pragma unroll
                for (int r = 0; r < 4; r++)
                    sm.Cv[nloc * 136 + wr * 64 + rt * 16 + quad * 4 + r] = f2bf(acc[rt][ct][r] + bias);
        }
        __syncthreads();
        #pragma unroll
        for (int p = 0; p < 6; p++) {
            int id = p * 256 + t;            // 1536 = 96 dd x 16 chunks
            int ddl = id >> 4;
            int sseg = (id & 15) * 8;
            short8 val = *(const short8*)(sm.Cv + ddl * 136 + sseg);
            int within = (n0 + ddl) - 1536;
            int head = within >> 6, dd = within & 63;
            *(short8*)(v_ws + (size_t)head * (HD * SEQ) + (size_t)dd * SEQ + m0 + sseg) = val;
        }
    }
}

// ---------------- Banded attention: 32 rows/WG, 512 threads, single-pass softmax ----------------
// grid 1536 (XCD-swizzled: 192 consecutive slots per XCD = 1.5 heads). Two 16-row
// blocks (rb) share fm + K-window. Pb holds UNNORMALIZED bf16 probs at ABSOLUTE
// column cc (key j0+cc, cc in [0,560)); row-block rb reads cc in [16rb, 16rb+544).
__global__ __launch_bounds__(512) void attn_kernel(
    const unsigned short* __restrict__ q_ws,
    const unsigned short* __restrict__ k_ws,
    const unsigned short* __restrict__ v_ws,
    const float* __restrict__ amask,
    const unsigned char* __restrict__ imask,
    float* __restrict__ out)
{
    const int lbid = blockIdx.x;
    const int xcd = lbid & 7, slot = lbid >> 3;
    const int w = xcd * 192 + slot;
    const int h = w >> 7, c = w & 127;
    const int i0 = c * 32;
    const int j0 = i0 - 256;
    const int t = threadIdx.x;
    const int wave = t >> 6, lane = t & 63;
    const int quad = lane >> 4, l16 = lane & 15;
    const int rb = wave >> 2, wsub = wave & 3;
    const int rbase = i0 + rb * 16;
    const bool interior = (j0 >= 0) && (j0 + 560 <= SEQ);

    __shared__ unsigned short Pb[32 * PSTR2];  // 37.1 KB unnormalized bf16 probs
    __shared__ float fm[560];                  // per-key mask (log2 domain)
    __shared__ float redB[32][4];              // cross-wave sum partials

    unsigned char imv[4];
    #pragma unroll
    for (int x = 0; x < 4; x++) imv[x] = imask[rbase + quad * 4 + x];

    for (int cc = t; cc < 560; cc += 512) {
        int j = j0 + cc;
        float f;
        if (interior)
            f = (amask[j] != 0.0f) ? LNEG * LOG2E : 0.0f;
        else
            f = (j < 0 || j >= SEQ) ? -1e30f : ((amask[j] != 0.0f) ? LNEG * LOG2E : 0.0f);
        fm[cc] = f;
    }
    {   // zero pad: rows 0..15 cols 528..543; rows 16..31 cols 544..559
        int r = t >> 4, col = t & 15;
        int cc = (r < 16 ? 528 : 544) + col;
        Pb[r * PSTR2 + cc] = 0;
    }

    const unsigned short* qbase = q_ws + h * (SEQ * HD) + (size_t)(rbase + l16) * HD + quad * 8;
    short8 a0 = *(const short8*)qbase;
    short8 a1 = *(const short8*)(qbase + 32);

    // ---- QK^T into registers: wave covers rel tiles {wsub+4i, i<9} of its rb ----
    f32x4 sc[9];
    const unsigned short* kh = k_ws + h * (SEQ * HD);
    #pragma unroll
    for (int i = 0; i < 9; i++) {
        int rel = wsub + 4 * i;
        if (rel < 33) {
            int j = j0 + (rel + rb) * 16 + l16;
            if (!interior) j = min(max(j, 0), SEQ - 1);
            const unsigned short* kb = kh + (size_t)j * HD + quad * 8;
            short8 b0 = *(const short8*)kb;
            short8 b1 = *(const short8*)(kb + 32);
            f32x4 s = {0.f, 0.f, 0.f, 0.f};
            s = __builtin_amdgcn_mfma_f32_16x16x32_bf16(a0, b0, s, 0, 0, 0);
            s = __builtin_amdgcn_mfma_f32_16x16x32_bf16(a1, b1, s, 0, 0, 0);
            sc[i] = s;
        }
    }
    __syncthreads();   // fm / pad visible

    // ---- single pass: band-mask + exp2 + bf16 store + row-sum ----
    f32x4 sum4 = {0.f, 0.f, 0.f, 0.f};
    #pragma unroll
    for (int i = 0; i < 9; i++) {
        int rel = wsub + 4 * i;
        if (rel < 33) {
            int cc = (rel + rb) * 16 + l16;        // absolute column
            float fmv = fm[cc];
            #pragma unroll
            for (int x = 0; x < 4; x++) {
                int rloc = quad * 4 + x;
                // band: cc_abs - row_glob = rel*16 + l16 - rloc
                float e = ((unsigned)(rel * 16 + l16 - rloc) <= 512u)
                              ? __builtin_amdgcn_exp2f(sc[i][x] + fmv) : 0.f;
                unsigned short pb = f2bf(e);
                Pb[(rb * 16 + rloc) * PSTR2 + cc] = pb;
                sum4[x] += bf2f(pb);
            }
        }
    }
    #pragma unroll
    for (int off = 1; off < 16; off <<= 1)
        #pragma unroll
        for (int x = 0; x < 4; x++)
            sum4[x] += __shfl_xor(sum4[x], off);
    if (l16 == 0) {
        #pragma unroll
        for (int x = 0; x < 4; x++) redB[rb * 16 + quad * 4 + x][wsub] = sum4[x];
    }
    __syncthreads();

    // ---- PV on unnormalized probs: wave = (rb, 16-wide d tile wsub) ----
    f32x4 o = {0.f, 0.f, 0.f, 0.f};
    const int dd = wsub * 16 + l16;
    const unsigned short* vbase = v_ws + h * (HD * SEQ) + (size_t)dd * SEQ;
    const unsigned short* prow = Pb + (rb * 16 + l16) * PSTR2 + rb * 16;
    if (interior) {
        #pragma unroll
        for (int kk = 0; kk < 17; kk++) {
            short8 af = *(const short8*)(prow + kk * 32 + quad * 8);
            short8 vb = *(const short8*)(vbase + j0 + rb * 16 + kk * 32 + quad * 8);
            o = __builtin_amdgcn_mfma_f32_16x16x32_bf16(af, vb, o, 0, 0, 0);
        }
    } else {
        #pragma unroll
        for (int kk = 0; kk < 17; kk++) {
            short8 af = *(const short8*)(prow + kk * 32 + quad * 8);
            int jb = j0 + rb * 16 + kk * 32 + quad * 8;
            jb = min(max(jb, 0), SEQ - 8);
            short8 vb = *(const short8*)(vbase + jb);
            o = __builtin_amdgcn_mfma_f32_16x16x32_bf16(af, vb, o, 0, 0, 0);
        }
    }

    float* obase = out + (size_t)(rbase + quad * 4) * EMB + h * HD + dd;
    #pragma unroll
    for (int r = 0; r < 4; r++) {
        const float* rr = redB[rb * 16 + quad * 4 + r];
        float tot = rr[0] + rr[1] + rr[2] + rr[3];
        float rinv = imv[r] ? 0.f : __builtin_amdgcn_rcpf(tot);
        obase[r * EMB] = o[r] * rinv;
    }
}

extern "C" void kernel_launch(void* const* d_in, const int* in_sizes, int n_in,
                              void* d_out, int out_size, void* d_ws, size_t ws_size,
                              hipStream_t stream) {
    (void)in_sizes; (void)n_in; (void)out_size; (void)ws_size;
    const float* hid = (const float*)d_in[0];
    const float* am  = (const float*)d_in[1];
    const unsigned char* im = (const unsigned char*)d_in[2];
    const float* Wq = (const float*)d_in[3];
    const float* bq = (const float*)d_in[4];
    const float* Wk = (const float*)d_in[5];
    const float* bk = (const float*)d_in[6];
    const float* Wv = (const float*)d_in[7];
    const float* bv = (const float*)d_in[8];
    float* out = (float*)d_out;

    unsigned short* ws = (unsigned short*)d_ws;
    unsigned short* q_ws = ws;
    unsigned short* k_ws = ws + (size_t)NH * SEQ * HD;
    unsigned short* v_ws = ws + 2 * (size_t)NH * SEQ * HD;
    unsigned short* hidb = (unsigned short*)d_out;   // d_out as scratch (attn overwrites last)
    unsigned short* Wt   = hidb + (size_t)SEQ * EMB;

    prep_kernel<<<dim3(1008), 256, 0, stream>>>(hid, Wq, Wk, Wv, hidb, Wt);
    gemm_kernel<<<dim3(32, 24), 256, 0, stream>>>(hidb, Wt, bq, bk, bv, q_ws, k_ws, v_ws);
    attn_kernel<<<dim3(1536), 512, 0, stream>>>(q_ws, k_ws, v_ws, am, im, out);
}

// Round 7
// 159.316 us; speedup vs baseline: 1.0439x; 1.0439x over previous
//
#include <hip/hip_runtime.h>

#define SEQ 4096
#define EMB 768
#define NH 12
#define HD 64
#define KDIM 768
#define LNEG -100000000.0f
#define LOG2E 1.44269504f
#define PSTR 548   // Pb row stride (shorts): verified 0 conflicts in R4/R5

typedef __attribute__((ext_vector_type(8))) short short8;
typedef __attribute__((ext_vector_type(4))) short short4v;
typedef __attribute__((ext_vector_type(4))) float f32x4;

__device__ inline unsigned short f2bf(float f) {
    unsigned int u = __float_as_uint(f);
    u += 0x7fffu + ((u >> 16) & 1u);
    return (unsigned short)(u >> 16);
}
__device__ inline float bf2f(unsigned short s) {
    unsigned int u = ((unsigned int)s) << 16;
    return __uint_as_float(u);
}

__device__ inline void gload_lds16(const unsigned short* g, unsigned short* l) {
    __builtin_amdgcn_global_load_lds(
        (const __attribute__((address_space(1))) void*)g,
        (__attribute__((address_space(3))) void*)l, 16, 0, 0);
}

// ---------------- Prep: hid -> bf16, W -> W^T bf16 (q-scale*log2e folded into Wq) ----------------
__global__ __launch_bounds__(256) void prep_kernel(
    const float* __restrict__ hid,
    const float* __restrict__ Wq, const float* __restrict__ Wk, const float* __restrict__ Wv,
    unsigned short* __restrict__ hidb,   // [4096][768] bf16
    unsigned short* __restrict__ Wt)     // [2304][768] bf16, [n][k]
{
    const int bid = blockIdx.x;
    const int t = threadIdx.x;
    if (bid >= 432) {
        int vid = (bid - 432) * 256 + t;
        const int nch = SEQ * EMB / 4;
        const int stride = 576 * 256;
        for (int c = vid; c < nch; c += stride) {
            f32x4 v = ((const f32x4*)hid)[c];
            short4v o;
            #pragma unroll
            for (int x = 0; x < 4; x++) o[x] = (short)f2bf(v[x]);
            ((short4v*)hidb)[c] = o;
        }
        return;
    }
    const int mat = bid / 144;
    const int r2 = bid % 144;
    const int k0 = (r2 % 12) * 64;
    const int n0 = (r2 / 12) * 64;
    const float* Wm = (mat == 0) ? Wq : (mat == 1 ? Wk : Wv);
    const float scale = (mat == 0) ? 0.125f * LOG2E : 1.0f;
    __shared__ unsigned short Lt[64 * 82];
    #pragma unroll
    for (int i = 0; i < 4; i++) {
        int row = i * 16 + (t >> 4);
        int col = (t & 15) * 4;
        f32x4 v = *(const f32x4*)(Wm + (size_t)(k0 + row) * EMB + n0 + col);
        #pragma unroll
        for (int x = 0; x < 4; x++)
            Lt[(col + x) * 82 + row] = f2bf(v[x] * scale);
    }
    __syncthreads();
    #pragma unroll
    for (int j = 0; j < 2; j++) {
        int idx = j * 256 + t;
        int nr = idx >> 3;
        int kc = (idx & 7) * 8;
        short8 o = *(const short8*)(Lt + nr * 82 + kc);
        *(short8*)(Wt + (size_t)(mat * 768 + n0 + nr) * KDIM + k0 + kc) = o;
    }
}

// ---------------- GEMM: 64x128 tiles, grid (64,18); LDS-bounce coalesced epilogue ----------------
__global__ __launch_bounds__(256) void gemm_kernel(
    const unsigned short* __restrict__ hidb,
    const unsigned short* __restrict__ Wt,
    const float* __restrict__ bq, const float* __restrict__ bk, const float* __restrict__ bv,
    unsigned short* __restrict__ q_ws,   // [H][S][D] bf16
    unsigned short* __restrict__ k_ws,   // [H][S][D] bf16
    unsigned short* __restrict__ v_ws)   // [H][D][S] bf16
{
    const int m0 = blockIdx.x * 64;
    const int n0 = blockIdx.y * 128;
    __shared__ union {
        struct { unsigned short Al[64 * 64]; unsigned short Bl[128 * 64]; } s;  // 24 KB
        unsigned short Cqk[64 * 136];   // 17.4 KB, stride 136 (272B, 16B-aligned rows)
        unsigned short Cv[128 * 72];    // 18.4 KB, stride 72 (144B, 16B-aligned rows)
    } sm;
    const int t = threadIdx.x;
    const int wave = t >> 6, lane = t & 63;
    const int quad = lane >> 4, l16 = lane & 15;

    const f32x4 zero = {0.f, 0.f, 0.f, 0.f};
    f32x4 acc[4][2];
    #pragma unroll
    for (int i = 0; i < 4; i++)
        #pragma unroll
        for (int j = 0; j < 2; j++) acc[i][j] = zero;

    for (int k0 = 0; k0 < KDIM; k0 += 64) {
        #pragma unroll
        for (int i = 0; i < 2; i++) {
            int c = (wave * 2 + i) * 64 + lane;
            int row = c >> 3;
            int kc = ((c & 7) ^ (row & 7)) * 8;
            gload_lds16(hidb + (size_t)(m0 + row) * KDIM + k0 + kc, sm.s.Al + (wave * 2 + i) * 512);
        }
        #pragma unroll
        for (int i = 0; i < 4; i++) {
            int c = (wave * 4 + i) * 64 + lane;
            int row = c >> 3;
            int kc = ((c & 7) ^ (row & 7)) * 8;
            gload_lds16(Wt + (size_t)(n0 + row) * KDIM + k0 + kc, sm.s.Bl + (wave * 4 + i) * 512);
        }
        __syncthreads();

        short8 af[2][4], bfr[2][2];
        #pragma unroll
        for (int rt = 0; rt < 4; rt++) {
            int rowA = rt * 16 + l16;
            #pragma unroll
            for (int s = 0; s < 2; s++)
                af[s][rt] = *(const short8*)(sm.s.Al + rowA * 64 + (((s << 2) | quad) ^ (rowA & 7)) * 8);
        }
        #pragma unroll
        for (int ct = 0; ct < 2; ct++) {
            int rowB = wave * 32 + ct * 16 + l16;
            #pragma unroll
            for (int s = 0; s < 2; s++)
                bfr[s][ct] = *(const short8*)(sm.s.Bl + rowB * 64 + (((s << 2) | quad) ^ (rowB & 7)) * 8);
        }
        #pragma unroll
        for (int s = 0; s < 2; s++)
            #pragma unroll
            for (int rt = 0; rt < 4; rt++)
                #pragma unroll
                for (int ct = 0; ct < 2; ct++)
                    acc[rt][ct] = __builtin_amdgcn_mfma_f32_16x16x32_bf16(af[s][rt], bfr[s][ct], acc[rt][ct], 0, 0, 0);
        __syncthreads();
    }

    const int mat = blockIdx.y / 6;
    const float* bm = (mat == 0) ? bq : (mat == 1 ? bk : bv);
    const float bscale = (mat == 0) ? 0.125f * LOG2E : 1.0f;

    if (mat != 2) {
        #pragma unroll
        for (int ct = 0; ct < 2; ct++) {
            int nloc = wave * 32 + ct * 16 + l16;
            float bias = bm[(n0 + nloc) - mat * 768] * bscale;
            #pragma unroll
            for (int rt = 0; rt < 4; rt++)
                #pragma unroll
                for (int r = 0; r < 4; r++)
                    sm.Cqk[(rt * 16 + quad * 4 + r) * 136 + nloc] = f2bf(acc[rt][ct][r] + bias);
        }
        __syncthreads();
        unsigned short* dst_ws = (mat == 0) ? q_ws : k_ws;
        #pragma unroll
        for (int p = 0; p < 4; p++) {
            int id = p * 256 + t;            // 1024 = 64 rows x 16 chunks
            int row = id >> 4, nc = id & 15;
            short8 val = *(const short8*)(sm.Cqk + row * 136 + nc * 8);
            int within = (n0 + nc * 8) - mat * 768;
            int head = within >> 6, dd = within & 63;
            *(short8*)(dst_ws + (size_t)head * (SEQ * HD) + (size_t)(m0 + row) * HD + dd) = val;
        }
    } else {
        #pragma unroll
        for (int ct = 0; ct < 2; ct++) {
            int nloc = wave * 32 + ct * 16 + l16;
            float bias = bm[(n0 + nloc) - 1536];
            #pragma unroll
            for (int rt = 0; rt < 4; rt++)
                #pragma unroll
                for (int r = 0; r < 4; r++)
                    sm.Cv[nloc * 72 + rt * 16 + quad * 4 + r] = f2bf(acc[rt][ct][r] + bias);
        }
        __syncthreads();
        #pragma unroll
        for (int p = 0; p < 4; p++) {
            int id = p * 256 + t;            // 1024 = 128 dd x 8 chunks
            int ddl = id >> 3;
            int sseg = (id & 7) * 8;
            short8 val = *(const short8*)(sm.Cv + ddl * 72 + sseg);
            int within = (n0 + ddl) - 1536;
            int head = within >> 6, dd = within & 63;
            *(short8*)(v_ws + (size_t)head * (HD * SEQ) + (size_t)dd * SEQ + m0 + sseg) = val;
        }
    }
}

// ---------------- Banded attention: register-pipelined K/V loads ----------------
// grid 3072 (XCD-swizzled), 256 threads, 16 rows/WG. QK in 3 groups of 3 tiles,
// double-buffered K fragments (6 loads in flight vs 2). PV in groups of 4 with
// prefetch; first V group issued before the barrier (drain completes it free).
__global__ __launch_bounds__(256) void attn_kernel(
    const unsigned short* __restrict__ q_ws,
    const unsigned short* __restrict__ k_ws,
    const unsigned short* __restrict__ v_ws,
    const float* __restrict__ amask,
    const unsigned char* __restrict__ imask,
    float* __restrict__ out)
{
    const int lbid = blockIdx.x;
    const int xcd = lbid & 7, slot = lbid >> 3;
    const int w = xcd * 384 + slot;
    const int h = w >> 8, c = w & 255;
    const int i0 = c * 16;
    const int j0 = i0 - 256;
    const int t = threadIdx.x;
    const int wave = t >> 6, lane = t & 63;
    const int quad = lane >> 4, l16 = lane & 15;
    const bool interior = (j0 >= 0) && (j0 + 544 <= SEQ);

    __shared__ unsigned short Pb[16 * PSTR];  // unnormalized bf16 probs
    __shared__ float fm[544];                 // per-key mask (log2 domain)
    __shared__ float redB[16][4];             // cross-wave sum partials

    unsigned char imv[4];
    #pragma unroll
    for (int x = 0; x < 4; x++) imv[x] = imask[i0 + quad * 4 + x];

    for (int cc = t; cc < 544; cc += 256) {
        int j = j0 + cc;
        float f;
        if (interior)
            f = (amask[j] != 0.0f) ? LNEG * LOG2E : 0.0f;
        else
            f = (j < 0 || j >= SEQ) ? -1e30f : ((amask[j] != 0.0f) ? LNEG * LOG2E : 0.0f);
        fm[cc] = f;
    }
    Pb[(t >> 4) * PSTR + 528 + (t & 15)] = 0;   // zero pad cols 528..543

    const unsigned short* qbase = q_ws + h * (SEQ * HD) + (size_t)(i0 + l16) * HD + quad * 8;
    short8 a0 = *(const short8*)qbase;
    short8 a1 = *(const short8*)(qbase + 32);

    // ---- QK^T: tiles {wave+4i, i<9}, grouped 3+3+3, double-buffered loads ----
    const unsigned short* kh = k_ws + h * (SEQ * HD);
    auto kaddr = [&](int i) {
        int tile = wave + 4 * i;
        int j = j0 + tile * 16 + l16;
        if (!interior) j = min(max(j, 0), SEQ - 1);
        return kh + (size_t)j * HD + quad * 8;
    };
    short8 kb[2][3][2];
    #pragma unroll
    for (int jj = 0; jj < 3; jj++) {
        const unsigned short* p = kaddr(jj);
        kb[0][jj][0] = *(const short8*)p;
        kb[0][jj][1] = *(const short8*)(p + 32);
    }
    f32x4 sc[9];
    #pragma unroll
    for (int g = 0; g < 3; g++) {
        if (g < 2) {
            #pragma unroll
            for (int jj = 0; jj < 3; jj++) {
                int i = (g + 1) * 3 + jj;
                if (i < 8 || wave == 0) {               // tile wave+4i < 33
                    const unsigned short* p = kaddr(i);
                    kb[(g + 1) & 1][jj][0] = *(const short8*)p;
                    kb[(g + 1) & 1][jj][1] = *(const short8*)(p + 32);
                }
            }
        }
        #pragma unroll
        for (int jj = 0; jj < 3; jj++) {
            int i = g * 3 + jj;
            if (i < 8 || wave == 0) {
                f32x4 s = {0.f, 0.f, 0.f, 0.f};
                s = __builtin_amdgcn_mfma_f32_16x16x32_bf16(a0, kb[g & 1][jj][0], s, 0, 0, 0);
                s = __builtin_amdgcn_mfma_f32_16x16x32_bf16(a1, kb[g & 1][jj][1], s, 0, 0, 0);
                sc[i] = s;
            }
        }
    }
    __syncthreads();   // fm / Pb-tail visible

    // ---- single pass: mask + exp2 + bf16 store + row-sum ----
    f32x4 sum4 = {0.f, 0.f, 0.f, 0.f};
    #pragma unroll
    for (int i = 0; i < 9; i++) {
        int tile = wave + 4 * i;
        if (tile < 33) {
            int cc = tile * 16 + l16;
            float fmv = fm[cc];
            #pragma unroll
            for (int x = 0; x < 4; x++) {
                int row = quad * 4 + x;
                float e = ((unsigned)(cc - row) <= 512u)
                              ? __builtin_amdgcn_exp2f(sc[i][x] + fmv) : 0.f;
                unsigned short pb = f2bf(e);
                Pb[row * PSTR + cc] = pb;
                sum4[x] += bf2f(pb);
            }
        }
    }
    #pragma unroll
    for (int off = 1; off < 16; off <<= 1)
        #pragma unroll
        for (int x = 0; x < 4; x++)
            sum4[x] += __shfl_xor(sum4[x], off);
    if (l16 == 0) {
        #pragma unroll
        for (int x = 0; x < 4; x++) redB[quad * 4 + x][wave] = sum4[x];
    }

    // ---- PV: prefetch V group 0 BEFORE the barrier (drain completes it) ----
    const int dd = wave * 16 + l16;
    const unsigned short* vbase = v_ws + h * (HD * SEQ) + (size_t)dd * SEQ;
    auto vaddr = [&](int kk) {
        int jb = j0 + kk * 32 + quad * 8;
        if (!interior) jb = min(max(jb, 0), SEQ - 8);
        return vbase + jb;
    };
    short8 vb[2][4];
    #pragma unroll
    for (int jj = 0; jj < 4; jj++) vb[0][jj] = *(const short8*)vaddr(jj);
    __syncthreads();   // Pb + redB visible

    f32x4 o = {0.f, 0.f, 0.f, 0.f};
    #pragma unroll
    for (int g = 0; g < 5; g++) {
        if (g < 4) {
            int cnt = (g == 3) ? 1 : 4;
            #pragma unroll
            for (int jj = 0; jj < 4; jj++)
                if (jj < cnt) vb[(g + 1) & 1][jj] = *(const short8*)vaddr((g + 1) * 4 + jj);
        }
        int nkk = (g == 4) ? 1 : 4;
        #pragma unroll
        for (int jj = 0; jj < 4; jj++)
            if (jj < nkk) {
                int kk = g * 4 + jj;
                short8 af = *(const short8*)(Pb + l16 * PSTR + kk * 32 + quad * 8);
                o = __builtin_amdgcn_mfma_f32_16x16x32_bf16(af, vb[g & 1][jj], o, 0, 0, 0);
            }
    }

    float* obase = out + (size_t)(i0 + quad * 4) * EMB + h * HD + dd;
    #pragma unroll
    for (int r = 0; r < 4; r++) {
        const float* rr = redB[quad * 4 + r];
        float tot = rr[0] + rr[1] + rr[2] + rr[3];
        float rinv = imv[r] ? 0.f : __builtin_amdgcn_rcpf(tot);
        obase[r * EMB] = o[r] * rinv;
    }
}

extern "C" void kernel_launch(void* const* d_in, const int* in_sizes, int n_in,
                              void* d_out, int out_size, void* d_ws, size_t ws_size,
                              hipStream_t stream) {
    (void)in_sizes; (void)n_in; (void)out_size; (void)ws_size;
    const float* hid = (const float*)d_in[0];
    const float* am  = (const float*)d_in[1];
    const unsigned char* im = (const unsigned char*)d_in[2];
    const float* Wq = (const float*)d_in[3];
    const float* bq = (const float*)d_in[4];
    const float* Wk = (const float*)d_in[5];
    const float* bk = (const float*)d_in[6];
    const float* Wv = (const float*)d_in[7];
    const float* bv = (const float*)d_in[8];
    float* out = (float*)d_out;

    unsigned short* ws = (unsigned short*)d_ws;
    unsigned short* q_ws = ws;
    unsigned short* k_ws = ws + (size_t)NH * SEQ * HD;
    unsigned short* v_ws = ws + 2 * (size_t)NH * SEQ * HD;
    unsigned short* hidb = (unsigned short*)d_out;   // d_out as scratch (attn overwrites last)
    unsigned short* Wt   = hidb + (size_t)SEQ * EMB;

    prep_kernel<<<dim3(1008), 256, 0, stream>>>(hid, Wq, Wk, Wv, hidb, Wt);
    gemm_kernel<<<dim3(64, 18), 256, 0, stream>>>(hidb, Wt, bq, bk, bv, q_ws, k_ws, v_ws);
    attn_kernel<<<dim3(3072), 256, 0, stream>>>(q_ws, k_ws, v_ws, am, im, out);
}

// Round 8
// 157.618 us; speedup vs baseline: 1.0551x; 1.0108x over previous
//
#include <hip/hip_runtime.h>

#define SEQ 4096
#define EMB 768
#define NH 12
#define HD 64
#define KDIM 768
#define LNEG -100000000.0f
#define LOG2E 1.44269504f
#define PSTR 548   // Pb row stride (shorts): verified 0 conflicts in R4/R5

typedef __attribute__((ext_vector_type(8))) short short8;
typedef __attribute__((ext_vector_type(4))) short short4v;
typedef __attribute__((ext_vector_type(4))) float f32x4;

__device__ inline unsigned short f2bf(float f) {
    unsigned int u = __float_as_uint(f);
    u += 0x7fffu + ((u >> 16) & 1u);
    return (unsigned short)(u >> 16);
}
__device__ inline float bf2f(unsigned short s) {
    unsigned int u = ((unsigned int)s) << 16;
    return __uint_as_float(u);
}

__device__ inline void gload_lds16(const unsigned short* g, unsigned short* l) {
    __builtin_amdgcn_global_load_lds(
        (const __attribute__((address_space(1))) void*)g,
        (__attribute__((address_space(3))) void*)l, 16, 0, 0);
}

// ---------------- Prep: hid -> bf16, W -> W^T bf16 (q-scale*log2e folded into Wq) ----------------
__global__ __launch_bounds__(256) void prep_kernel(
    const float* __restrict__ hid,
    const float* __restrict__ Wq, const float* __restrict__ Wk, const float* __restrict__ Wv,
    unsigned short* __restrict__ hidb,   // [4096][768] bf16
    unsigned short* __restrict__ Wt)     // [2304][768] bf16, [n][k]
{
    const int bid = blockIdx.x;
    const int t = threadIdx.x;
    if (bid >= 432) {
        int vid = (bid - 432) * 256 + t;
        const int nch = SEQ * EMB / 4;
        const int stride = 576 * 256;
        for (int c = vid; c < nch; c += stride) {
            f32x4 v = ((const f32x4*)hid)[c];
            short4v o;
            #pragma unroll
            for (int x = 0; x < 4; x++) o[x] = (short)f2bf(v[x]);
            ((short4v*)hidb)[c] = o;
        }
        return;
    }
    const int mat = bid / 144;
    const int r2 = bid % 144;
    const int k0 = (r2 % 12) * 64;
    const int n0 = (r2 / 12) * 64;
    const float* Wm = (mat == 0) ? Wq : (mat == 1 ? Wk : Wv);
    const float scale = (mat == 0) ? 0.125f * LOG2E : 1.0f;
    __shared__ unsigned short Lt[64 * 82];
    #pragma unroll
    for (int i = 0; i < 4; i++) {
        int row = i * 16 + (t >> 4);
        int col = (t & 15) * 4;
        f32x4 v = *(const f32x4*)(Wm + (size_t)(k0 + row) * EMB + n0 + col);
        #pragma unroll
        for (int x = 0; x < 4; x++)
            Lt[(col + x) * 82 + row] = f2bf(v[x] * scale);
    }
    __syncthreads();
    #pragma unroll
    for (int j = 0; j < 2; j++) {
        int idx = j * 256 + t;
        int nr = idx >> 3;
        int kc = (idx & 7) * 8;
        short8 o = *(const short8*)(Lt + nr * 82 + kc);
        *(short8*)(Wt + (size_t)(mat * 768 + n0 + nr) * KDIM + k0 + kc) = o;
    }
}

// ---------------- GEMM: 64x128 tiles, grid (64,18); LDS-bounce coalesced epilogue ----------------
__global__ __launch_bounds__(256) void gemm_kernel(
    const unsigned short* __restrict__ hidb,
    const unsigned short* __restrict__ Wt,
    const float* __restrict__ bq, const float* __restrict__ bk, const float* __restrict__ bv,
    unsigned short* __restrict__ q_ws,   // [H][S][D] bf16
    unsigned short* __restrict__ k_ws,   // [H][S][D] bf16
    unsigned short* __restrict__ v_ws)   // [H][D][S] bf16
{
    const int m0 = blockIdx.x * 64;
    const int n0 = blockIdx.y * 128;
    __shared__ union {
        struct { unsigned short Al[64 * 64]; unsigned short Bl[128 * 64]; } s;  // 24 KB
        unsigned short Cqk[64 * 136];   // 17.4 KB, stride 136 (272B, 16B-aligned rows)
        unsigned short Cv[128 * 72];    // 18.4 KB, stride 72 (144B, 16B-aligned rows)
    } sm;
    const int t = threadIdx.x;
    const int wave = t >> 6, lane = t & 63;
    const int quad = lane >> 4, l16 = lane & 15;

    const f32x4 zero = {0.f, 0.f, 0.f, 0.f};
    f32x4 acc[4][2];
    #pragma unroll
    for (int i = 0; i < 4; i++)
        #pragma unroll
        for (int j = 0; j < 2; j++) acc[i][j] = zero;

    for (int k0 = 0; k0 < KDIM; k0 += 64) {
        #pragma unroll
        for (int i = 0; i < 2; i++) {
            int c = (wave * 2 + i) * 64 + lane;
            int row = c >> 3;
            int kc = ((c & 7) ^ (row & 7)) * 8;
            gload_lds16(hidb + (size_t)(m0 + row) * KDIM + k0 + kc, sm.s.Al + (wave * 2 + i) * 512);
        }
        #pragma unroll
        for (int i = 0; i < 4; i++) {
            int c = (wave * 4 + i) * 64 + lane;
            int row = c >> 3;
            int kc = ((c & 7) ^ (row & 7)) * 8;
            gload_lds16(Wt + (size_t)(n0 + row) * KDIM + k0 + kc, sm.s.Bl + (wave * 4 + i) * 512);
        }
        __syncthreads();

        short8 af[2][4], bfr[2][2];
        #pragma unroll
        for (int rt = 0; rt < 4; rt++) {
            int rowA = rt * 16 + l16;
            #pragma unroll
            for (int s = 0; s < 2; s++)
                af[s][rt] = *(const short8*)(sm.s.Al + rowA * 64 + (((s << 2) | quad) ^ (rowA & 7)) * 8);
        }
        #pragma unroll
        for (int ct = 0; ct < 2; ct++) {
            int rowB = wave * 32 + ct * 16 + l16;
            #pragma unroll
            for (int s = 0; s < 2; s++)
                bfr[s][ct] = *(const short8*)(sm.s.Bl + rowB * 64 + (((s << 2) | quad) ^ (rowB & 7)) * 8);
        }
        #pragma unroll
        for (int s = 0; s < 2; s++)
            #pragma unroll
            for (int rt = 0; rt < 4; rt++)
                #pragma unroll
                for (int ct = 0; ct < 2; ct++)
                    acc[rt][ct] = __builtin_amdgcn_mfma_f32_16x16x32_bf16(af[s][rt], bfr[s][ct], acc[rt][ct], 0, 0, 0);
        __syncthreads();
    }

    const int mat = blockIdx.y / 6;
    const float* bm = (mat == 0) ? bq : (mat == 1 ? bk : bv);
    const float bscale = (mat == 0) ? 0.125f * LOG2E : 1.0f;

    if (mat != 2) {
        #pragma unroll
        for (int ct = 0; ct < 2; ct++) {
            int nloc = wave * 32 + ct * 16 + l16;
            float bias = bm[(n0 + nloc) - mat * 768] * bscale;
            #pragma unroll
            for (int rt = 0; rt < 4; rt++)
                #pragma unroll
                for (int r = 0; r < 4; r++)
                    sm.Cqk[(rt * 16 + quad * 4 + r) * 136 + nloc] = f2bf(acc[rt][ct][r] + bias);
        }
        __syncthreads();
        unsigned short* dst_ws = (mat == 0) ? q_ws : k_ws;
        #pragma unroll
        for (int p = 0; p < 4; p++) {
            int id = p * 256 + t;            // 1024 = 64 rows x 16 chunks
            int row = id >> 4, nc = id & 15;
            short8 val = *(const short8*)(sm.Cqk + row * 136 + nc * 8);
            int within = (n0 + nc * 8) - mat * 768;
            int head = within >> 6, dd = within & 63;
            *(short8*)(dst_ws + (size_t)head * (SEQ * HD) + (size_t)(m0 + row) * HD + dd) = val;
        }
    } else {
        #pragma unroll
        for (int ct = 0; ct < 2; ct++) {
            int nloc = wave * 32 + ct * 16 + l16;
            float bias = bm[(n0 + nloc) - 1536];
            #pragma unroll
            for (int rt = 0; rt < 4; rt++)
                #pragma unroll
                for (int r = 0; r < 4; r++)
                    sm.Cv[nloc * 72 + rt * 16 + quad * 4 + r] = f2bf(acc[rt][ct][r] + bias);
        }
        __syncthreads();
        #pragma unroll
        for (int p = 0; p < 4; p++) {
            int id = p * 256 + t;            // 1024 = 128 dd x 8 chunks
            int ddl = id >> 3;
            int sseg = (id & 7) * 8;
            short8 val = *(const short8*)(sm.Cv + ddl * 72 + sseg);
            int within = (n0 + ddl) - 1536;
            int head = within >> 6, dd = within & 63;
            *(short8*)(v_ws + (size_t)head * (HD * SEQ) + (size_t)dd * SEQ + m0 + sseg) = val;
        }
    }
}

// ---------------- Banded attention: flat loops, UNCAPPED VGPR budget ----------------
// grid 3072 (XCD-swizzled), 256 threads, 16 rows/WG. __launch_bounds__(256,1):
// only ~12 WGs/CU of work exist, so occupancy is worthless — spend VGPRs on
// keeping all 18 QK and 17 PV loads in flight (R5-R7 were stuck at VGPR=60,
// which forces serialized load->wait->MFMA chains; that was the ~57 us floor).
__global__ __launch_bounds__(256, 1) void attn_kernel(
    const unsigned short* __restrict__ q_ws,
    const unsigned short* __restrict__ k_ws,
    const unsigned short* __restrict__ v_ws,
    const float* __restrict__ amask,
    const unsigned char* __restrict__ imask,
    float* __restrict__ out)
{
    const int lbid = blockIdx.x;
    const int xcd = lbid & 7, slot = lbid >> 3;
    const int w = xcd * 384 + slot;
    const int h = w >> 8, c = w & 255;
    const int i0 = c * 16;
    const int j0 = i0 - 256;
    const int t = threadIdx.x;
    const int wave = t >> 6, lane = t & 63;
    const int quad = lane >> 4, l16 = lane & 15;
    const bool interior = (j0 >= 0) && (j0 + 544 <= SEQ);

    __shared__ unsigned short Pb[16 * PSTR];  // unnormalized bf16 probs
    __shared__ float fm[544];                 // per-key mask (log2 domain)
    __shared__ float redB[16][4];             // cross-wave sum partials

    unsigned char imv[4];
    #pragma unroll
    for (int x = 0; x < 4; x++) imv[x] = imask[i0 + quad * 4 + x];

    for (int cc = t; cc < 544; cc += 256) {
        int j = j0 + cc;
        float f;
        if (interior)
            f = (amask[j] != 0.0f) ? LNEG * LOG2E : 0.0f;
        else
            f = (j < 0 || j >= SEQ) ? -1e30f : ((amask[j] != 0.0f) ? LNEG * LOG2E : 0.0f);
        fm[cc] = f;
    }
    Pb[(t >> 4) * PSTR + 528 + (t & 15)] = 0;   // zero pad cols 528..543

    const unsigned short* qbase = q_ws + h * (SEQ * HD) + (size_t)(i0 + l16) * HD + quad * 8;
    short8 a0 = *(const short8*)qbase;
    short8 a1 = *(const short8*)(qbase + 32);

    // ---- QK^T into registers: tiles {wave+4i, i<9}; flat unrolled loop ----
    f32x4 sc[9];
    const unsigned short* kh = k_ws + h * (SEQ * HD);
    if (interior) {
        #pragma unroll
        for (int i = 0; i < 9; i++) {
            int tile = wave + 4 * i;
            if (tile < 33) {
                const unsigned short* kb = kh + (size_t)(j0 + tile * 16 + l16) * HD + quad * 8;
                short8 b0 = *(const short8*)kb;
                short8 b1 = *(const short8*)(kb + 32);
                f32x4 s = {0.f, 0.f, 0.f, 0.f};
                s = __builtin_amdgcn_mfma_f32_16x16x32_bf16(a0, b0, s, 0, 0, 0);
                s = __builtin_amdgcn_mfma_f32_16x16x32_bf16(a1, b1, s, 0, 0, 0);
                sc[i] = s;
            }
        }
    } else {
        #pragma unroll
        for (int i = 0; i < 9; i++) {
            int tile = wave + 4 * i;
            if (tile < 33) {
                int j = j0 + tile * 16 + l16;
                int jc = min(max(j, 0), SEQ - 1);
                const unsigned short* kb = kh + (size_t)jc * HD + quad * 8;
                short8 b0 = *(const short8*)kb;
                short8 b1 = *(const short8*)(kb + 32);
                f32x4 s = {0.f, 0.f, 0.f, 0.f};
                s = __builtin_amdgcn_mfma_f32_16x16x32_bf16(a0, b0, s, 0, 0, 0);
                s = __builtin_amdgcn_mfma_f32_16x16x32_bf16(a1, b1, s, 0, 0, 0);
                sc[i] = s;
            }
        }
    }
    __syncthreads();   // fm / Pb-tail visible

    // ---- single pass: mask + exp2 + bf16 store + row-sum ----
    f32x4 sum4 = {0.f, 0.f, 0.f, 0.f};
    #pragma unroll
    for (int i = 0; i < 9; i++) {
        int tile = wave + 4 * i;
        if (tile < 33) {
            int cc = tile * 16 + l16;
            float fmv = fm[cc];
            #pragma unroll
            for (int x = 0; x < 4; x++) {
                int row = quad * 4 + x;
                float e = ((unsigned)(cc - row) <= 512u)
                              ? __builtin_amdgcn_exp2f(sc[i][x] + fmv) : 0.f;
                unsigned short pb = f2bf(e);
                Pb[row * PSTR + cc] = pb;
                sum4[x] += bf2f(pb);
            }
        }
    }
    #pragma unroll
    for (int off = 1; off < 16; off <<= 1)
        #pragma unroll
        for (int x = 0; x < 4; x++)
            sum4[x] += __shfl_xor(sum4[x], off);
    if (l16 == 0) {
        #pragma unroll
        for (int x = 0; x < 4; x++) redB[quad * 4 + x][wave] = sum4[x];
    }
    __syncthreads();

    // ---- PV on unnormalized probs: flat unrolled loop ----
    f32x4 o = {0.f, 0.f, 0.f, 0.f};
    const int dd = wave * 16 + l16;
    const unsigned short* vbase = v_ws + h * (HD * SEQ) + (size_t)dd * SEQ;
    if (interior) {
        #pragma unroll
        for (int kk = 0; kk < 17; kk++) {
            short8 af = *(const short8*)(Pb + l16 * PSTR + kk * 32 + quad * 8);
            short8 vb = *(const short8*)(vbase + j0 + kk * 32 + quad * 8);
            o = __builtin_amdgcn_mfma_f32_16x16x32_bf16(af, vb, o, 0, 0, 0);
        }
    } else {
        #pragma unroll
        for (int kk = 0; kk < 17; kk++) {
            short8 af = *(const short8*)(Pb + l16 * PSTR + kk * 32 + quad * 8);
            int jb = j0 + kk * 32 + quad * 8;
            jb = min(max(jb, 0), SEQ - 8);
            short8 vb = *(const short8*)(vbase + jb);
            o = __builtin_amdgcn_mfma_f32_16x16x32_bf16(af, vb, o, 0, 0, 0);
        }
    }

    float* obase = out + (size_t)(i0 + quad * 4) * EMB + h * HD + dd;
    #pragma unroll
    for (int r = 0; r < 4; r++) {
        const float* rr = redB[quad * 4 + r];
        float tot = rr[0] + rr[1] + rr[2] + rr[3];
        float rinv = imv[r] ? 0.f : __builtin_amdgcn_rcpf(tot);
        obase[r * EMB] = o[r] * rinv;
    }
}

extern "C" void kernel_launch(void* const* d_in, const int* in_sizes, int n_in,
                              void* d_out, int out_size, void* d_ws, size_t ws_size,
                              hipStream_t stream) {
    (void)in_sizes; (void)n_in; (void)out_size; (void)ws_size;
    const float* hid = (const float*)d_in[0];
    const float* am  = (const float*)d_in[1];
    const unsigned char* im = (const unsigned char*)d_in[2];
    const float* Wq = (const float*)d_in[3];
    const float* bq = (const float*)d_in[4];
    const float* Wk = (const float*)d_in[5];
    const float* bk = (const float*)d_in[6];
    const float* Wv = (const float*)d_in[7];
    const float* bv = (const float*)d_in[8];
    float* out = (float*)d_out;

    unsigned short* ws = (unsigned short*)d_ws;
    unsigned short* q_ws = ws;
    unsigned short* k_ws = ws + (size_t)NH * SEQ * HD;
    unsigned short* v_ws = ws + 2 * (size_t)NH * SEQ * HD;
    unsigned short* hidb = (unsigned short*)d_out;   // d_out as scratch (attn overwrites last)
    unsigned short* Wt   = hidb + (size_t)SEQ * EMB;

    prep_kernel<<<dim3(1008), 256, 0, stream>>>(hid, Wq, Wk, Wv, hidb, Wt);
    gemm_kernel<<<dim3(64, 18), 256, 0, stream>>>(hidb, Wt, bq, bk, bv, q_ws, k_ws, v_ws);
    attn_kernel<<<dim3(3072), 256, 0, stream>>>(q_ws, k_ws, v_ws, am, im, out);
}